// Round 9
// baseline (191.481 us; speedup 1.0000x reference)
//
#include <hip/hip_runtime.h>
#include <math.h>

#define LSEQ 4096
#define NFFT 4096      // complex FFT length (real length 8192 via packing)
#define NM   64
#define NBH  4096

__device__ __forceinline__ float2 cmulf(float2 a, float2 b) {
  return make_float2(a.x*b.x - a.y*b.y, a.x*b.y + a.y*b.x);
}
// a * conj(b)
__device__ __forceinline__ float2 cmulc(float2 a, float2 b) {
  return make_float2(a.x*b.x + a.y*b.y, a.y*b.x - a.x*b.y);
}
__device__ __forceinline__ float2 caddf(float2 a, float2 b){ return make_float2(a.x+b.x, a.y+b.y); }
__device__ __forceinline__ float2 csubf(float2 a, float2 b){ return make_float2(a.x-b.x, a.y-b.y); }

// base-4 digit swap of a 4-bit value: reg r holds freq digit RHO(r) after fused r16
__host__ __device__ constexpr int RHO(int d){ return ((d&3)<<2) | (d>>2); }

// storage swizzle: phys[3:0]^=l[7:4], phys[7:4]^=l[11:8] -> all passes at b64 bank floor
__device__ __forceinline__ int ZS(int i){ return i ^ ((i>>4)&15) ^ (((i>>8)&15)<<4); }

// ---- radix-4 butterflies (validated r1..r8 lineage) ----
__device__ __forceinline__ void r4_fwd(float2& x0, float2& x1, float2& x2, float2& x3,
                                       float2 w1, float2 w2, float2 w3) {
  float2 A = caddf(x0,x2), C = csubf(x0,x2);
  float2 B = caddf(x1,x3), D = csubf(x1,x3);
  float2 y1 = make_float2(C.x + D.y, C.y - D.x);   // C - iD
  float2 y3 = make_float2(C.x - D.y, C.y + D.x);   // C + iD
  x0 = caddf(A,B);
  x1 = cmulf(y1,w1);
  x2 = cmulf(csubf(A,B),w2);
  x3 = cmulf(y3,w3);
}
// inverse butterfly taking FORWARD twiddles (conj applied inside, free)
__device__ __forceinline__ void r4_invc(float2& y0, float2& y1, float2& y2, float2& y3,
                                        float2 w1, float2 w2, float2 w3) {
  float2 c1 = cmulc(y1,w1);
  float2 c2 = cmulc(y2,w2);
  float2 c3 = cmulc(y3,w3);
  float2 ap = caddf(y0,c2), bp = csubf(y0,c2);
  float2 cp = caddf(c1,c3);
  float2 dp = make_float2(c3.y - c1.y, c1.x - c3.x);  // i*(c1-c3)
  y0 = caddf(ap,cp); y1 = caddf(bp,dp); y2 = csubf(ap,cp); y3 = csubf(bp,dp);
}

#define DECL_CONSTS \
  const float C16R[4]={1.f,0.9238795325112867f,0.7071067811865476f,0.3826834323650898f}; \
  const float C16I[4]={0.f,-0.3826834323650898f,-0.7071067811865476f,-0.9238795325112867f}; \
  const float C8R[4] ={1.f,0.7071067811865476f,0.f,-0.7071067811865476f}; \
  const float C8I[4] ={0.f,-0.7071067811865476f,-1.f,-0.7071067811865476f}; \
  const float C163R[4]={1.f,0.3826834323650898f,-0.7071067811865476f,-0.9238795325112867f}; \
  const float C163I[4]={0.f,-0.9238795325112867f,-0.7071067811865476f,0.3826834323650898f};

__device__ __forceinline__ void r16_fwd1(float2 x[16]) {
  DECL_CONSTS
  #pragma unroll
  for (int k0 = 0; k0 < 4; k0++)
    r4_fwd(x[k0], x[k0+4], x[k0+8], x[k0+12],
           make_float2(C16R[k0],C16I[k0]), make_float2(C8R[k0],C8I[k0]),
           make_float2(C163R[k0],C163I[k0]));
  #pragma unroll
  for (int q = 0; q < 4; q++)
    r4_fwd(x[4*q], x[4*q+1], x[4*q+2], x[4*q+3],
           make_float2(1.f,0.f), make_float2(1.f,0.f), make_float2(1.f,0.f));
}
__device__ __forceinline__ void r16_inv1(float2 x[16]) {
  DECL_CONSTS
  #pragma unroll
  for (int q = 0; q < 4; q++)
    r4_invc(x[4*q], x[4*q+1], x[4*q+2], x[4*q+3],
            make_float2(1.f,0.f), make_float2(1.f,0.f), make_float2(1.f,0.f));
  #pragma unroll
  for (int k0 = 0; k0 < 4; k0++)
    r4_invc(x[k0], x[k0+4], x[k0+8], x[k0+12],
            make_float2(C16R[k0],C16I[k0]), make_float2(C8R[k0],C8I[k0]),
            make_float2(C163R[k0],C163I[k0]));
}
// table packs: w[0..3]=w1[k0], [4..7]=w2[k0], [8..11]=w3[k0], [12..14]=wB,wB2,wB3
__device__ __forceinline__ void r16_fwd_t(float2 x[16], const float4 tp[8]) {
  float2 tw[16];
  #pragma unroll
  for (int q = 0; q < 8; q++) {
    tw[2*q]   = make_float2(tp[q].x, tp[q].y);
    tw[2*q+1] = make_float2(tp[q].z, tp[q].w);
  }
  #pragma unroll
  for (int k0 = 0; k0 < 4; k0++)
    r4_fwd(x[k0], x[k0+4], x[k0+8], x[k0+12], tw[k0], tw[4+k0], tw[8+k0]);
  #pragma unroll
  for (int q = 0; q < 4; q++)
    r4_fwd(x[4*q], x[4*q+1], x[4*q+2], x[4*q+3], tw[12], tw[13], tw[14]);
}
__device__ __forceinline__ void r16_inv_t(float2 x[16], const float4 tp[8]) {
  float2 tw[16];
  #pragma unroll
  for (int q = 0; q < 8; q++) {
    tw[2*q]   = make_float2(tp[q].x, tp[q].y);
    tw[2*q+1] = make_float2(tp[q].z, tp[q].w);
  }
  #pragma unroll
  for (int q = 0; q < 4; q++)
    r4_invc(x[4*q], x[4*q+1], x[4*q+2], x[4*q+3], tw[12], tw[13], tw[14]);
  #pragma unroll
  for (int k0 = 0; k0 < 4; k0++)
    r4_invc(x[k0], x[k0+4], x[k0+8], x[k0+12], tw[k0], tw[4+k0], tw[8+k0]);
}

// ---------------- prep: twiddle-pack tables, one entry per thread ----------------
__device__ __forceinline__ double slotExpo(int s, int t) {   // 1/4096 units
  if (s < 4)  return (double)(t + 256*s);
  if (s < 8)  return (double)(2*t + 512*(s-4));
  if (s < 12) return (double)(3*t + 768*(s-8));
  if (s == 12) return (double)(4*t);
  if (s == 13) return (double)(8*t);
  if (s == 14) return (double)(12*t);
  return 0.0;
}
__device__ __forceinline__ float2 E4096(double e) {
  double ang = -2.0*M_PI*e/4096.0;
  return make_float2((float)cos(ang), (float)sin(ang));
}
__global__ void tables_kernel(float4* __restrict__ tp1, float4* __restrict__ tp2,
                              float2* __restrict__ wp3) {
  int idx = blockIdx.x*blockDim.x + threadIdx.x;
  if (idx < 2048) {                       // tp1[q*256+t], wA = W4096^t
    int q = idx >> 8, t = idx & 255;
    float2 wa = E4096(slotExpo(2*q,   t));
    float2 wb = E4096(slotExpo(2*q+1, t));
    tp1[q*256 + t] = make_float4(wa.x, wa.y, wb.x, wb.y);
  } else if (idx < 2176) {                // tp2[q*16+j], wA = W256^j = W4096^{16j}
    int r = idx - 2048; int q = r >> 4, j = r & 15;
    float2 wa = E4096(slotExpo(2*q,   16*j));
    float2 wb = E4096(slotExpo(2*q+1, 16*j));
    tp2[q*16 + j] = make_float4(wa.x, wa.y, wb.x, wb.y);
  } else if (idx < 2432) {                // wp3[b] = W8192^{RHO(b>>4)+16*RHO(b&15)}
    int b = idx - 2176;
    int e = RHO(b>>4) + 16*RHO(b&15);
    double ang = -2.0*M_PI*(double)e/8192.0;
    wp3[b] = make_float2((float)cos(ang), (float)sin(ang));
  }
}

// ---------------- prep: at_roots via 4 Cauchy dots (fp64) -- unchanged ----------------
__global__ void cauchy_kernel(const float* __restrict__ Lre, const float* __restrict__ Lim,
                              const float* __restrict__ Pre, const float* __restrict__ Pim,
                              const float* __restrict__ Bre, const float* __restrict__ Bim,
                              const float* __restrict__ Cri, const float* __restrict__ lstep,
                              float2* __restrict__ a_out) {
  int k = blockIdx.x*blockDim.x + threadIdx.x;
  if (k >= LSEQ) return;
  double step = exp((double)lstep[0]);
  double ang = -2.0*M_PI*(double)k/(double)LSEQ;
  double wr = cos(ang), wi = sin(ang);
  double nr = 1.0 - wr, ni = -wi;
  double dr = 1.0 + wr, di = wi;
  double dn = dr*dr + di*di;
  double gre = (2.0/step) * (nr*dr + ni*di)/dn;
  double gim = (2.0/step) * (ni*dr - nr*di)/dn;
  double cre = 2.0*dr/dn, cim = -2.0*di/dn;
  double k00r=0,k00i=0,k01r=0,k01i=0,k10r=0,k10i=0,k11r=0,k11i=0;
  for (int n = 0; n < NM; n++) {
    double lre = Lre[n], lim = Lim[n];
    double pre = Pre[n], pim = Pim[n];
    double bre = Bre[n], bim = Bim[n];
    double ccr = Cri[2*n], cci = Cri[2*n+1];
    double er = gre - lre, ei = gim - lim;
    double inv = 1.0/(er*er + ei*ei);
    double ir =  er*inv, ii = -ei*inv;
    double v00r = ccr*bre + cci*bim, v00i = ccr*bim - cci*bre;
    double v01r = ccr*pre + cci*pim, v01i = ccr*pim - cci*pre;
    double v10r = pre*bre + pim*bim, v10i = pre*bim - pim*bre;
    double v11r = pre*pre + pim*pim, v11i = 0.0;
    k00r += v00r*ir - v00i*ii;  k00i += v00r*ii + v00i*ir;
    k01r += v01r*ir - v01i*ii;  k01i += v01r*ii + v01i*ir;
    k10r += v10r*ir - v10i*ii;  k10i += v10r*ii + v10i*ir;
    k11r += v11r*ir - v11i*ii;  k11i += v11r*ii + v11i*ir;
  }
  double numr = k01r*k10r - k01i*k10i, numi = k01r*k10i + k01i*k10r;
  double der = 1.0 + k11r, dei = k11i;
  double dinv = 1.0/(der*der + dei*dei);
  double qr = (numr*der + numi*dei)*dinv;
  double qi = (numi*der - numr*dei)*dinv;
  double tr = k00r - qr, ti = k00i - qi;
  double ar = cre*tr - cim*ti, ai = cre*ti + cim*tr;
  a_out[k] = make_float2((float)ar, (float)ai);
}

// ---------------- prep: K[l] = Re(IDFT_L(a))[l], 64 lanes per output ----------------
__global__ void ktime_kernel(const float2* __restrict__ a, float* __restrict__ K) {
  int lane = threadIdx.x & 63;
  int l = blockIdx.x * (blockDim.x >> 6) + (threadIdx.x >> 6);
  if (l >= LSEQ) return;
  double ang0 = 2.0*M_PI*(double)((l*lane) & (LSEQ-1))/(double)LSEQ;
  double tr = cos(ang0), ti = sin(ang0);
  double ang1 = 2.0*M_PI*(double)(l & 63)/64.0;
  double wr = cos(ang1), wi = sin(ang1);
  double acc = 0.0;
  for (int k = 0; k < 64; k++) {
    float2 ak = a[lane + (k << 6)];
    acc += (double)ak.x*tr - (double)ak.y*ti;
    double ntr = tr*wr - ti*wi;
    ti = tr*wi + ti*wr;
    tr = ntr;
  }
  for (int off = 32; off > 0; off >>= 1) acc += __shfl_down(acc, off);
  if (lane == 0) K[l] = (float)(acc/(double)LSEQ);
}

// ---------------- prep: H[k] = sum_l K[l] W8192^{kl}, k=0..4096 (fp64 direct) ----------
__global__ void hspec_kernel(const float* __restrict__ K, float2* __restrict__ H) {
  int lane = threadIdx.x & 63;
  int k = blockIdx.x * (blockDim.x >> 6) + (threadIdx.x >> 6);
  if (k > NFFT) return;
  int m0 = (k*lane) & 8191;
  double a0 = -2.0*M_PI*(double)m0/8192.0;
  double cr = cos(a0), ci = sin(a0);
  int ms = (k << 6) & 8191;
  double as = -2.0*M_PI*(double)ms/8192.0;
  double sr = cos(as), si = sin(as);
  double accr = 0.0, acci = 0.0;
  for (int j = 0; j < 64; j++) {
    double Kv = (double)K[lane + (j << 6)];
    accr += Kv*cr; acci += Kv*ci;
    double nr2 = cr*sr - ci*si;
    ci = cr*si + ci*sr; cr = nr2;
  }
  for (int off = 32; off > 0; off >>= 1) {
    accr += __shfl_down(accr, off);
    acci += __shfl_down(acci, off);
  }
  if (lane == 0) H[k] = make_float2((float)accr, (float)acci);
}

// ---------------- prep: lay H out per (block,reg) with D folded and 1/16384 scale ------
__global__ void map_kernel(const float2* __restrict__ H, const float* __restrict__ Dp,
                           float2* __restrict__ KdA, float2* __restrict__ KdB) {
  int idx = blockIdx.x*blockDim.x + threadIdx.x;
  if (idx >= NFFT) return;
  int b = idx >> 4, c = idx & 15;
  int k = RHO(b>>4) + 16*RHO(b&15) + 256*RHO(c);
  const float s = 1.0f/16384.0f;
  float Dv = Dp[0];
  float2 ha = H[k], hb = H[NFFT - k];
  KdA[idx] = make_float2((ha.x + Dv)*s, ha.y*s);
  KdB[idx] = make_float2((hb.x + Dv)*s, hb.y*s);
}

// ---------------- main: 1 row/block, packed real-8192 FFT as complex-4096 ----------------
// 256 thr (4 waves), 32KB LDS. __launch_bounds__(256,1): empirical toolchain rule is
// VGPR cap = 256/arg2 ((512,4)->64, (256,4)->64, (512,2)->128, (256,2)->128-and-spilled).
// arg2=1 -> cap 256: kernel allocates its natural ~140-180 VGPR with ZERO spill;
// occupancy 8 waves/CU (2 blocks). r8 at cap 128 spilled ~150MB scratch (WRITE 216MB).
__global__ __launch_bounds__(256, 1)
void conv_kernel(const float* __restrict__ u,
                 const float4* __restrict__ tp1, const float4* __restrict__ tp2,
                 const float2* __restrict__ wp3, const float2* __restrict__ KdA,
                 const float2* __restrict__ KdB, float* __restrict__ out) {
  __shared__ float2 z[NFFT];
  const int tid = threadIdx.x;
  const float2* u2 = (const float2*)(u + (size_t)blockIdx.x*LSEQ);
  float2 x[16];
  // ---- P1: load packed row, r16 fwd (stride 256) ----
  {
    float4 tpr[8];
    #pragma unroll
    for (int q = 0; q < 8; q++) tpr[q] = tp1[(q<<8) + tid];
    #pragma unroll
    for (int k = 0; k < 8; k++) x[k] = u2[tid + (k<<8)];
    #pragma unroll
    for (int k = 8; k < 16; k++) x[k] = make_float2(0.f, 0.f);
    r16_fwd_t(x, tpr);
    #pragma unroll
    for (int k = 0; k < 16; k++) z[ZS(tid + (k<<8))] = x[k];
  }
  __syncthreads();
  // ---- P2: r16 fwd (stride 16) ----
  const int j4 = tid & 15, gb = (tid>>4)<<8;
  {
    float4 tq[8];
    #pragma unroll
    for (int q = 0; q < 8; q++) tq[q] = tp2[(q<<4) + j4];
    #pragma unroll
    for (int k = 0; k < 16; k++) x[k] = z[ZS(gb + (k<<4) + j4)];
    r16_fwd_t(x, tq);
    #pragma unroll
    for (int k = 0; k < 16; k++) z[ZS(gb + (k<<4) + j4)] = x[k];
  }
  __syncthreads();
  // ---- P3a: final r16 fwd, publish spectrum to LDS (x stays in regs) ----
  // block assignment: group g handles high digit Hmap[g]; pairs co-wave
  const int h16 = (int)((0xA9B8C7D6E5F42310ull >> ((tid>>4)<<2)) & 15);
  const int b = (h16<<4) | j4;
  int pb;
  if (tid >= 16) pb = (RHO(16 - RHO(b>>4)) << 4) | (15 - j4);
  else           pb = (tid == 0) ? 0 : RHO(16 - RHO(tid));
  const int bb = b<<4, pbb = pb<<4;
  {
    #pragma unroll
    for (int c = 0; c < 16; c++) x[c] = z[ZS(bb + c)];
    r16_fwd1(x);    // x[c] = Z[k(b,c)], k = RHO(b>>4)+16*RHO(b&15)+256*RHO(c)
    #pragma unroll
    for (int c = 0; c < 16; c++) z[ZS(bb + c)] = x[c];
  }
  __syncthreads();
  // ---- P3b: spectral op; z is READ-ONLY here (mirrors read one at a time) ----
  {
    const float2 wbase = wp3[b];
    const float4* KdA4 = (const float4*)(KdA + bb);
    const float4* KdB4 = (const float4*)(KdB + bb);
    // W32^{RHO(c)} = exp(-i*pi*RHO(c)/16)
    const float CW32R[16] = {1.f,0.7071067811865476f,0.f,-0.7071067811865476f,
                             0.9807852804032304f,0.5555702330196022f,-0.19509032201612825f,-0.8314696123025452f,
                             0.9238795325112867f,0.3826834323650898f,-0.3826834323650898f,-0.9238795325112867f,
                             0.8314696123025452f,0.19509032201612825f,-0.5555702330196022f,-0.9807852804032304f};
    const float CW32I[16] = {0.f,-0.7071067811865476f,-1.f,-0.7071067811865476f,
                             -0.19509032201612825f,-0.8314696123025452f,-0.9807852804032304f,-0.5555702330196022f,
                             -0.3826834323650898f,-0.9238795325112867f,-0.9238795325112867f,-0.3826834323650898f,
                             -0.5555702330196022f,-0.9807852804032304f,-0.8314696123025452f,-0.19509032201612825f};
    const int M0T[16] = {0,3,2,1,15,14,13,12,11,10,9,8,7,6,5,4};
    const bool t0 = (tid == 0);
    #pragma unroll
    for (int c2 = 0; c2 < 8; c2++) {
      float4 a4 = KdA4[c2], b4 = KdB4[c2];
      #pragma unroll
      for (int cc = 0; cc < 2; cc++) {
        const int c = 2*c2 + cc;
        float2 kda = cc ? make_float2(a4.z, a4.w) : make_float2(a4.x, a4.y);
        float2 kdb = cc ? make_float2(b4.z, b4.w) : make_float2(b4.x, b4.y);
        const int mc = t0 ? M0T[c] : (15 - c);
        float2 Zo = x[c];
        float2 Zm = z[ZS(pbb + mc)];
        float2 wk = cmulf(wbase, make_float2(CW32R[c], CW32I[c]));  // W8192^k
        float Sx = Zo.x + Zm.x, Sy = Zo.y - Zm.y;    // S = Zo + conj(Zm)
        float Dx = Zo.x - Zm.x, Dy = Zo.y + Zm.y;    // D = Zo - conj(Zm)
        float2 t1 = cmulf(wk, make_float2(Dx, Dy));
        float2 Up = make_float2(Sx + t1.y, Sy - t1.x);    // U'  = S - i*t1
        float2 Um = make_float2(Sx - t1.y, -Sy - t1.x);   // U'm = conj(S) - i*conj(t1)
        float2 Yp = cmulf(Up, kda);                        // ~ Y[k]
        float2 Ym = cmulf(Um, kdb);                        // ~ Y[N-k]
        float Pxx = Yp.x + Ym.x, Pyy = Yp.y - Ym.y;       // Y' + conj(Ym)
        float Qx  = Yp.x - Ym.x, Qy  = Yp.y + Ym.y;       // Y' - conj(Ym)
        float2 t2 = cmulc(make_float2(Qx, Qy), wk);        // Q * conj(wk)
        x[c] = make_float2(Pxx - t2.y, Pyy + t2.x);        // V = P + i*t2
      }
    }
  }
  __syncthreads();
  // ---- P3c: r16 inv (const twiddles), write back ----
  {
    r16_inv1(x);
    #pragma unroll
    for (int c = 0; c < 16; c++) z[ZS(bb + c)] = x[c];
  }
  __syncthreads();
  // ---- P4: r16 inv (stride 16) ----
  {
    float4 tq[8];
    #pragma unroll
    for (int q = 0; q < 8; q++) tq[q] = tp2[(q<<4) + j4];
    #pragma unroll
    for (int k = 0; k < 16; k++) x[k] = z[ZS(gb + (k<<4) + j4)];
    r16_inv_t(x, tq);
    #pragma unroll
    for (int k = 0; k < 16; k++) z[ZS(gb + (k<<4) + j4)] = x[k];
  }
  __syncthreads();
  // ---- P5: r16 inv (stride 256), unpack v[n] = (y[2n], y[2n+1]) ----
  {
    float4 tpr[8];
    #pragma unroll
    for (int q = 0; q < 8; q++) tpr[q] = tp1[(q<<8) + tid];
    #pragma unroll
    for (int k = 0; k < 16; k++) x[k] = z[ZS(tid + (k<<8))];
    r16_inv_t(x, tpr);
    float2* o2 = (float2*)(out + (size_t)blockIdx.x*LSEQ);
    #pragma unroll
    for (int k = 0; k < 8; k++) o2[tid + (k<<8)] = x[k];
  }
}

extern "C" void kernel_launch(void* const* d_in, const int* in_sizes, int n_in,
                              void* d_out, int out_size, void* d_ws, size_t ws_size,
                              hipStream_t stream) {
  const float* u     = (const float*)d_in[0];
  const float* Lre   = (const float*)d_in[1];
  const float* Lim   = (const float*)d_in[2];
  const float* Pre   = (const float*)d_in[3];
  const float* Pim   = (const float*)d_in[4];
  const float* Bre   = (const float*)d_in[5];
  const float* Bim   = (const float*)d_in[6];
  const float* Cri   = (const float*)d_in[7];
  const float* Dp    = (const float*)d_in[8];
  const float* lstep = (const float*)d_in[9];
  float* out = (float*)d_out;

  char* ws = (char*)d_ws;
  float2* a_ws   = (float2*)(ws);             //  32768 B : at_roots
  float*  K_ws   = (float*)(ws + 32768);      //  16384 B : K time domain
  float4* tp1_ws = (float4*)(ws + 49152);     //  32768 B : P1/P5 packs [8][256]
  float4* tp2_ws = (float4*)(ws + 81920);     //   2048 B : P2/P4 packs [8][16]
  float2* wp3_ws = (float2*)(ws + 83968);     //   2048 B : per-block W8192 base
  float2* H_ws   = (float2*)(ws + 86016);     //  32776 B : half-spectrum H[0..4096]
  float2* KdA_ws = (float2*)(ws + 118800);    //  32768 B : H[k] per (block,reg)
  float2* KdB_ws = (float2*)(ws + 151568);    //  32768 B : H[N-k] per (block,reg)

  hipLaunchKernelGGL(tables_kernel, dim3(10),   dim3(256), 0, stream,
                     tp1_ws, tp2_ws, wp3_ws);
  hipLaunchKernelGGL(cauchy_kernel, dim3(64),   dim3(64),  0, stream,
                     Lre, Lim, Pre, Pim, Bre, Bim, Cri, lstep, a_ws);
  hipLaunchKernelGGL(ktime_kernel,  dim3(1024), dim3(256), 0, stream, a_ws, K_ws);
  hipLaunchKernelGGL(hspec_kernel,  dim3(1025), dim3(256), 0, stream, K_ws, H_ws);
  hipLaunchKernelGGL(map_kernel,    dim3(16),   dim3(256), 0, stream,
                     H_ws, Dp, KdA_ws, KdB_ws);
  hipLaunchKernelGGL(conv_kernel,   dim3(NBH),  dim3(256), 0, stream,
                     u, tp1_ws, tp2_ws, wp3_ws, KdA_ws, KdB_ws, out);
}

// Round 10
// 172.085 us; speedup vs baseline: 1.1127x; 1.1127x over previous
//
#include <hip/hip_runtime.h>
#include <math.h>

#define LSEQ 4096
#define NFFT 4096      // complex FFT length (real length 8192 via packing)
#define NM   64
#define NBH  4096

__device__ __forceinline__ float2 cmulf(float2 a, float2 b) {
  return make_float2(a.x*b.x - a.y*b.y, a.x*b.y + a.y*b.x);
}
// a * conj(b)
__device__ __forceinline__ float2 cmulc(float2 a, float2 b) {
  return make_float2(a.x*b.x + a.y*b.y, a.y*b.x - a.x*b.y);
}
__device__ __forceinline__ float2 caddf(float2 a, float2 b){ return make_float2(a.x+b.x, a.y+b.y); }
__device__ __forceinline__ float2 csubf(float2 a, float2 b){ return make_float2(a.x-b.x, a.y-b.y); }

// base-4 digit swap of a 4-bit value: reg r holds freq digit RHO(r) after fused r16
__host__ __device__ constexpr int RHO(int d){ return ((d&3)<<2) | (d>>2); }

// storage swizzle: phys[3:0]^=l[7:4], phys[7:4]^=l[11:8] -> all passes at b64 bank floor
__device__ __forceinline__ int ZS(int i){ return i ^ ((i>>4)&15) ^ (((i>>8)&15)<<4); }

// ---- radix-4 butterflies (validated r1..r9 lineage) ----
__device__ __forceinline__ void r4_fwd(float2& x0, float2& x1, float2& x2, float2& x3,
                                       float2 w1, float2 w2, float2 w3) {
  float2 A = caddf(x0,x2), C = csubf(x0,x2);
  float2 B = caddf(x1,x3), D = csubf(x1,x3);
  float2 y1 = make_float2(C.x + D.y, C.y - D.x);   // C - iD
  float2 y3 = make_float2(C.x - D.y, C.y + D.x);   // C + iD
  x0 = caddf(A,B);
  x1 = cmulf(y1,w1);
  x2 = cmulf(csubf(A,B),w2);
  x3 = cmulf(y3,w3);
}
// inverse butterfly taking FORWARD twiddles (conj applied inside, free)
__device__ __forceinline__ void r4_invc(float2& y0, float2& y1, float2& y2, float2& y3,
                                        float2 w1, float2 w2, float2 w3) {
  float2 c1 = cmulc(y1,w1);
  float2 c2 = cmulc(y2,w2);
  float2 c3 = cmulc(y3,w3);
  float2 ap = caddf(y0,c2), bp = csubf(y0,c2);
  float2 cp = caddf(c1,c3);
  float2 dp = make_float2(c3.y - c1.y, c1.x - c3.x);  // i*(c1-c3)
  y0 = caddf(ap,cp); y1 = caddf(bp,dp); y2 = csubf(ap,cp); y3 = csubf(bp,dp);
}

#define DECL_CONSTS \
  const float C16R[4]={1.f,0.9238795325112867f,0.7071067811865476f,0.3826834323650898f}; \
  const float C16I[4]={0.f,-0.3826834323650898f,-0.7071067811865476f,-0.9238795325112867f}; \
  const float C8R[4] ={1.f,0.7071067811865476f,0.f,-0.7071067811865476f}; \
  const float C8I[4] ={0.f,-0.7071067811865476f,-1.f,-0.7071067811865476f}; \
  const float C163R[4]={1.f,0.3826834323650898f,-0.7071067811865476f,-0.9238795325112867f}; \
  const float C163I[4]={0.f,-0.9238795325112867f,-0.7071067811865476f,0.3826834323650898f};

__device__ __forceinline__ void r16_fwd1(float2 x[16]) {
  DECL_CONSTS
  #pragma unroll
  for (int k0 = 0; k0 < 4; k0++)
    r4_fwd(x[k0], x[k0+4], x[k0+8], x[k0+12],
           make_float2(C16R[k0],C16I[k0]), make_float2(C8R[k0],C8I[k0]),
           make_float2(C163R[k0],C163I[k0]));
  #pragma unroll
  for (int q = 0; q < 4; q++)
    r4_fwd(x[4*q], x[4*q+1], x[4*q+2], x[4*q+3],
           make_float2(1.f,0.f), make_float2(1.f,0.f), make_float2(1.f,0.f));
}
__device__ __forceinline__ void r16_inv1(float2 x[16]) {
  DECL_CONSTS
  #pragma unroll
  for (int q = 0; q < 4; q++)
    r4_invc(x[4*q], x[4*q+1], x[4*q+2], x[4*q+3],
            make_float2(1.f,0.f), make_float2(1.f,0.f), make_float2(1.f,0.f));
  #pragma unroll
  for (int k0 = 0; k0 < 4; k0++)
    r4_invc(x[k0], x[k0+4], x[k0+8], x[k0+12],
            make_float2(C16R[k0],C16I[k0]), make_float2(C8R[k0],C8I[k0]),
            make_float2(C163R[k0],C163I[k0]));
}

// ---- register-diet table-twiddle radix-16: staged loads, direct consumption ----
// layout (per r9): tw[2q]=(tp[q].x,.y), tw[2q+1]=(tp[q].z,.w);
// w1[k0]=tw[k0], w2[k0]=tw[4+k0], w3[k0]=tw[8+k0]; wB=tw[12], wB2=tw[13], wB3=tw[14].
// k0=0,1 need tp0,tp2,tp4; k0=2,3 need tp1,tp3,tp5; level 2 needs tp6,tp7.
// Peak twiddle regs ~16 vs the old tp[8]+tw[16]=64 (the r8/r9 148-VGPR culprit).
__device__ __forceinline__ void r16_fwd_g(float2 x[16], const float4* __restrict__ tpb,
                                          const int st) {
  {
    float4 a0 = tpb[0], a2 = tpb[2*st], a4 = tpb[4*st];
    r4_fwd(x[0], x[4], x[8], x[12], make_float2(a0.x,a0.y), make_float2(a2.x,a2.y), make_float2(a4.x,a4.y));
    r4_fwd(x[1], x[5], x[9], x[13], make_float2(a0.z,a0.w), make_float2(a2.z,a2.w), make_float2(a4.z,a4.w));
  }
  {
    float4 a1 = tpb[st], a3 = tpb[3*st], a5 = tpb[5*st];
    r4_fwd(x[2], x[6], x[10], x[14], make_float2(a1.x,a1.y), make_float2(a3.x,a3.y), make_float2(a5.x,a5.y));
    r4_fwd(x[3], x[7], x[11], x[15], make_float2(a1.z,a1.w), make_float2(a3.z,a3.w), make_float2(a5.z,a5.w));
  }
  {
    float4 a6 = tpb[6*st], a7 = tpb[7*st];
    float2 wB = make_float2(a6.x,a6.y), wB2 = make_float2(a6.z,a6.w), wB3 = make_float2(a7.x,a7.y);
    #pragma unroll
    for (int q = 0; q < 4; q++)
      r4_fwd(x[4*q], x[4*q+1], x[4*q+2], x[4*q+3], wB, wB2, wB3);
  }
}
__device__ __forceinline__ void r16_inv_g(float2 x[16], const float4* __restrict__ tpb,
                                          const int st) {
  {
    float4 a6 = tpb[6*st], a7 = tpb[7*st];
    float2 wB = make_float2(a6.x,a6.y), wB2 = make_float2(a6.z,a6.w), wB3 = make_float2(a7.x,a7.y);
    #pragma unroll
    for (int q = 0; q < 4; q++)
      r4_invc(x[4*q], x[4*q+1], x[4*q+2], x[4*q+3], wB, wB2, wB3);
  }
  {
    float4 a0 = tpb[0], a2 = tpb[2*st], a4 = tpb[4*st];
    r4_invc(x[0], x[4], x[8], x[12], make_float2(a0.x,a0.y), make_float2(a2.x,a2.y), make_float2(a4.x,a4.y));
    r4_invc(x[1], x[5], x[9], x[13], make_float2(a0.z,a0.w), make_float2(a2.z,a2.w), make_float2(a4.z,a4.w));
  }
  {
    float4 a1 = tpb[st], a3 = tpb[3*st], a5 = tpb[5*st];
    r4_invc(x[2], x[6], x[10], x[14], make_float2(a1.x,a1.y), make_float2(a3.x,a3.y), make_float2(a5.x,a5.y));
    r4_invc(x[3], x[7], x[11], x[15], make_float2(a1.z,a1.w), make_float2(a3.z,a3.w), make_float2(a5.z,a5.w));
  }
}

// ---------------- prep: twiddle-pack tables, one entry per thread ----------------
__device__ __forceinline__ double slotExpo(int s, int t) {   // 1/4096 units
  if (s < 4)  return (double)(t + 256*s);
  if (s < 8)  return (double)(2*t + 512*(s-4));
  if (s < 12) return (double)(3*t + 768*(s-8));
  if (s == 12) return (double)(4*t);
  if (s == 13) return (double)(8*t);
  if (s == 14) return (double)(12*t);
  return 0.0;
}
__device__ __forceinline__ float2 E4096(double e) {
  double ang = -2.0*M_PI*e/4096.0;
  return make_float2((float)cos(ang), (float)sin(ang));
}
__global__ void tables_kernel(float4* __restrict__ tp1, float4* __restrict__ tp2,
                              float2* __restrict__ wp3) {
  int idx = blockIdx.x*blockDim.x + threadIdx.x;
  if (idx < 2048) {                       // tp1[q*256+t], wA = W4096^t
    int q = idx >> 8, t = idx & 255;
    float2 wa = E4096(slotExpo(2*q,   t));
    float2 wb = E4096(slotExpo(2*q+1, t));
    tp1[q*256 + t] = make_float4(wa.x, wa.y, wb.x, wb.y);
  } else if (idx < 2176) {                // tp2[q*16+j], wA = W256^j = W4096^{16j}
    int r = idx - 2048; int q = r >> 4, j = r & 15;
    float2 wa = E4096(slotExpo(2*q,   16*j));
    float2 wb = E4096(slotExpo(2*q+1, 16*j));
    tp2[q*16 + j] = make_float4(wa.x, wa.y, wb.x, wb.y);
  } else if (idx < 2432) {                // wp3[b] = W8192^{RHO(b>>4)+16*RHO(b&15)}
    int b = idx - 2176;
    int e = RHO(b>>4) + 16*RHO(b&15);
    double ang = -2.0*M_PI*(double)e/8192.0;
    wp3[b] = make_float2((float)cos(ang), (float)sin(ang));
  }
}

// ---------------- prep: at_roots via 4 Cauchy dots (fp64) -- unchanged ----------------
__global__ void cauchy_kernel(const float* __restrict__ Lre, const float* __restrict__ Lim,
                              const float* __restrict__ Pre, const float* __restrict__ Pim,
                              const float* __restrict__ Bre, const float* __restrict__ Bim,
                              const float* __restrict__ Cri, const float* __restrict__ lstep,
                              float2* __restrict__ a_out) {
  int k = blockIdx.x*blockDim.x + threadIdx.x;
  if (k >= LSEQ) return;
  double step = exp((double)lstep[0]);
  double ang = -2.0*M_PI*(double)k/(double)LSEQ;
  double wr = cos(ang), wi = sin(ang);
  double nr = 1.0 - wr, ni = -wi;
  double dr = 1.0 + wr, di = wi;
  double dn = dr*dr + di*di;
  double gre = (2.0/step) * (nr*dr + ni*di)/dn;
  double gim = (2.0/step) * (ni*dr - nr*di)/dn;
  double cre = 2.0*dr/dn, cim = -2.0*di/dn;
  double k00r=0,k00i=0,k01r=0,k01i=0,k10r=0,k10i=0,k11r=0,k11i=0;
  for (int n = 0; n < NM; n++) {
    double lre = Lre[n], lim = Lim[n];
    double pre = Pre[n], pim = Pim[n];
    double bre = Bre[n], bim = Bim[n];
    double ccr = Cri[2*n], cci = Cri[2*n+1];
    double er = gre - lre, ei = gim - lim;
    double inv = 1.0/(er*er + ei*ei);
    double ir =  er*inv, ii = -ei*inv;
    double v00r = ccr*bre + cci*bim, v00i = ccr*bim - cci*bre;
    double v01r = ccr*pre + cci*pim, v01i = ccr*pim - cci*pre;
    double v10r = pre*bre + pim*bim, v10i = pre*bim - pim*bre;
    double v11r = pre*pre + pim*pim, v11i = 0.0;
    k00r += v00r*ir - v00i*ii;  k00i += v00r*ii + v00i*ir;
    k01r += v01r*ir - v01i*ii;  k01i += v01r*ii + v01i*ir;
    k10r += v10r*ir - v10i*ii;  k10i += v10r*ii + v10i*ir;
    k11r += v11r*ir - v11i*ii;  k11i += v11r*ii + v11i*ir;
  }
  double numr = k01r*k10r - k01i*k10i, numi = k01r*k10i + k01i*k10r;
  double der = 1.0 + k11r, dei = k11i;
  double dinv = 1.0/(der*der + dei*dei);
  double qr = (numr*der + numi*dei)*dinv;
  double qi = (numi*der - numr*dei)*dinv;
  double tr = k00r - qr, ti = k00i - qi;
  double ar = cre*tr - cim*ti, ai = cre*ti + cim*tr;
  a_out[k] = make_float2((float)ar, (float)ai);
}

// ---------------- prep: K[l] = Re(IDFT_L(a))[l], 64 lanes per output ----------------
__global__ void ktime_kernel(const float2* __restrict__ a, float* __restrict__ K) {
  int lane = threadIdx.x & 63;
  int l = blockIdx.x * (blockDim.x >> 6) + (threadIdx.x >> 6);
  if (l >= LSEQ) return;
  double ang0 = 2.0*M_PI*(double)((l*lane) & (LSEQ-1))/(double)LSEQ;
  double tr = cos(ang0), ti = sin(ang0);
  double ang1 = 2.0*M_PI*(double)(l & 63)/64.0;
  double wr = cos(ang1), wi = sin(ang1);
  double acc = 0.0;
  for (int k = 0; k < 64; k++) {
    float2 ak = a[lane + (k << 6)];
    acc += (double)ak.x*tr - (double)ak.y*ti;
    double ntr = tr*wr - ti*wi;
    ti = tr*wi + ti*wr;
    tr = ntr;
  }
  for (int off = 32; off > 0; off >>= 1) acc += __shfl_down(acc, off);
  if (lane == 0) K[l] = (float)(acc/(double)LSEQ);
}

// ---------------- prep: H[k] = sum_l K[l] W8192^{kl}, k=0..4096 (fp64 direct) ----------
__global__ void hspec_kernel(const float* __restrict__ K, float2* __restrict__ H) {
  int lane = threadIdx.x & 63;
  int k = blockIdx.x * (blockDim.x >> 6) + (threadIdx.x >> 6);
  if (k > NFFT) return;
  int m0 = (k*lane) & 8191;
  double a0 = -2.0*M_PI*(double)m0/8192.0;
  double cr = cos(a0), ci = sin(a0);
  int ms = (k << 6) & 8191;
  double as = -2.0*M_PI*(double)ms/8192.0;
  double sr = cos(as), si = sin(as);
  double accr = 0.0, acci = 0.0;
  for (int j = 0; j < 64; j++) {
    double Kv = (double)K[lane + (j << 6)];
    accr += Kv*cr; acci += Kv*ci;
    double nr2 = cr*sr - ci*si;
    ci = cr*si + ci*sr; cr = nr2;
  }
  for (int off = 32; off > 0; off >>= 1) {
    accr += __shfl_down(accr, off);
    acci += __shfl_down(acci, off);
  }
  if (lane == 0) H[k] = make_float2((float)accr, (float)acci);
}

// ---------------- prep: lay H out per (block,reg) with D folded and 1/16384 scale ------
__global__ void map_kernel(const float2* __restrict__ H, const float* __restrict__ Dp,
                           float2* __restrict__ KdA, float2* __restrict__ KdB) {
  int idx = blockIdx.x*blockDim.x + threadIdx.x;
  if (idx >= NFFT) return;
  int b = idx >> 4, c = idx & 15;
  int k = RHO(b>>4) + 16*RHO(b&15) + 256*RHO(c);
  const float s = 1.0f/16384.0f;
  float Dv = Dp[0];
  float2 ha = H[k], hb = H[NFFT - k];
  KdA[idx] = make_float2((ha.x + Dv)*s, ha.y*s);
  KdB[idx] = make_float2((hb.x + Dv)*s, hb.y*s);
}

// ---------------- main: 1 row/block, packed real-8192 FFT as complex-4096 ----------------
// 256 thr (4 waves), 32KB LDS, (256,2) -> cap 128. Register diet vs r8/r9: staged
// twiddle consumption (r16_*_g) removed the tp[8]+tw[16]=64-reg twiddle state that
// pushed the natural allocation to 148 (r9) / spilled at cap 128 (r8, 150MB scratch).
// Target: <=128 VGPR, no spill, 4 blocks/CU = 16 waves/CU.
__global__ __launch_bounds__(256, 2)
void conv_kernel(const float* __restrict__ u,
                 const float4* __restrict__ tp1, const float4* __restrict__ tp2,
                 const float2* __restrict__ wp3, const float2* __restrict__ KdA,
                 const float2* __restrict__ KdB, float* __restrict__ out) {
  __shared__ float2 z[NFFT];
  const int tid = threadIdx.x;
  const float2* u2 = (const float2*)(u + (size_t)blockIdx.x*LSEQ);
  float2 x[16];
  // ---- P1: load packed row, r16 fwd (stride 256) ----
  {
    #pragma unroll
    for (int k = 0; k < 8; k++) x[k] = u2[tid + (k<<8)];
    #pragma unroll
    for (int k = 8; k < 16; k++) x[k] = make_float2(0.f, 0.f);
    r16_fwd_g(x, tp1 + tid, 256);
    #pragma unroll
    for (int k = 0; k < 16; k++) z[ZS(tid + (k<<8))] = x[k];
  }
  __syncthreads();
  // ---- P2: r16 fwd (stride 16) ----
  const int j4 = tid & 15, gb = (tid>>4)<<8;
  {
    #pragma unroll
    for (int k = 0; k < 16; k++) x[k] = z[ZS(gb + (k<<4) + j4)];
    r16_fwd_g(x, tp2 + j4, 16);
    #pragma unroll
    for (int k = 0; k < 16; k++) z[ZS(gb + (k<<4) + j4)] = x[k];
  }
  __syncthreads();
  // ---- P3a: final r16 fwd, publish spectrum to LDS (x stays in regs) ----
  // block assignment: group g handles high digit Hmap[g]; pairs co-wave
  const int h16 = (int)((0xA9B8C7D6E5F42310ull >> ((tid>>4)<<2)) & 15);
  const int b = (h16<<4) | j4;
  int pb;
  if (tid >= 16) pb = (RHO(16 - RHO(b>>4)) << 4) | (15 - j4);
  else           pb = (tid == 0) ? 0 : RHO(16 - RHO(tid));
  const int bb = b<<4, pbb = pb<<4;
  {
    #pragma unroll
    for (int c = 0; c < 16; c++) x[c] = z[ZS(bb + c)];
    r16_fwd1(x);    // x[c] = Z[k(b,c)], k = RHO(b>>4)+16*RHO(b&15)+256*RHO(c)
    #pragma unroll
    for (int c = 0; c < 16; c++) z[ZS(bb + c)] = x[c];
  }
  __syncthreads();
  // ---- P3b: spectral op; z is READ-ONLY here (mirrors read one at a time) ----
  {
    const float2 wbase = wp3[b];
    const float4* KdA4 = (const float4*)(KdA + bb);
    const float4* KdB4 = (const float4*)(KdB + bb);
    // W32^{RHO(c)} = exp(-i*pi*RHO(c)/16)
    const float CW32R[16] = {1.f,0.7071067811865476f,0.f,-0.7071067811865476f,
                             0.9807852804032304f,0.5555702330196022f,-0.19509032201612825f,-0.8314696123025452f,
                             0.9238795325112867f,0.3826834323650898f,-0.3826834323650898f,-0.9238795325112867f,
                             0.8314696123025452f,0.19509032201612825f,-0.5555702330196022f,-0.9807852804032304f};
    const float CW32I[16] = {0.f,-0.7071067811865476f,-1.f,-0.7071067811865476f,
                             -0.19509032201612825f,-0.8314696123025452f,-0.9807852804032304f,-0.5555702330196022f,
                             -0.3826834323650898f,-0.9238795325112867f,-0.9238795325112867f,-0.3826834323650898f,
                             -0.5555702330196022f,-0.9807852804032304f,-0.8314696123025452f,-0.19509032201612825f};
    const int M0T[16] = {0,3,2,1,15,14,13,12,11,10,9,8,7,6,5,4};
    const bool t0 = (tid == 0);
    #pragma unroll
    for (int c2 = 0; c2 < 8; c2++) {
      float4 a4 = KdA4[c2], b4 = KdB4[c2];
      #pragma unroll
      for (int cc = 0; cc < 2; cc++) {
        const int c = 2*c2 + cc;
        float2 kda = cc ? make_float2(a4.z, a4.w) : make_float2(a4.x, a4.y);
        float2 kdb = cc ? make_float2(b4.z, b4.w) : make_float2(b4.x, b4.y);
        const int mc = t0 ? M0T[c] : (15 - c);
        float2 Zo = x[c];
        float2 Zm = z[ZS(pbb + mc)];
        float2 wk = cmulf(wbase, make_float2(CW32R[c], CW32I[c]));  // W8192^k
        float Sx = Zo.x + Zm.x, Sy = Zo.y - Zm.y;    // S = Zo + conj(Zm)
        float Dx = Zo.x - Zm.x, Dy = Zo.y + Zm.y;    // D = Zo - conj(Zm)
        float2 t1 = cmulf(wk, make_float2(Dx, Dy));
        float2 Up = make_float2(Sx + t1.y, Sy - t1.x);    // U'  = S - i*t1
        float2 Um = make_float2(Sx - t1.y, -Sy - t1.x);   // U'm = conj(S) - i*conj(t1)
        float2 Yp = cmulf(Up, kda);                        // ~ Y[k]
        float2 Ym = cmulf(Um, kdb);                        // ~ Y[N-k]
        float Pxx = Yp.x + Ym.x, Pyy = Yp.y - Ym.y;       // Y' + conj(Ym)
        float Qx  = Yp.x - Ym.x, Qy  = Yp.y + Ym.y;       // Y' - conj(Ym)
        float2 t2 = cmulc(make_float2(Qx, Qy), wk);        // Q * conj(wk)
        x[c] = make_float2(Pxx - t2.y, Pyy + t2.x);        // V = P + i*t2
      }
    }
  }
  __syncthreads();
  // ---- P3c: r16 inv (const twiddles), write back ----
  {
    r16_inv1(x);
    #pragma unroll
    for (int c = 0; c < 16; c++) z[ZS(bb + c)] = x[c];
  }
  __syncthreads();
  // ---- P4: r16 inv (stride 16) ----
  {
    #pragma unroll
    for (int k = 0; k < 16; k++) x[k] = z[ZS(gb + (k<<4) + j4)];
    r16_inv_g(x, tp2 + j4, 16);
    #pragma unroll
    for (int k = 0; k < 16; k++) z[ZS(gb + (k<<4) + j4)] = x[k];
  }
  __syncthreads();
  // ---- P5: r16 inv (stride 256), unpack v[n] = (y[2n], y[2n+1]) ----
  {
    #pragma unroll
    for (int k = 0; k < 16; k++) x[k] = z[ZS(tid + (k<<8))];
    r16_inv_g(x, tp1 + tid, 256);
    float2* o2 = (float2*)(out + (size_t)blockIdx.x*LSEQ);
    #pragma unroll
    for (int k = 0; k < 8; k++) o2[tid + (k<<8)] = x[k];
  }
}

extern "C" void kernel_launch(void* const* d_in, const int* in_sizes, int n_in,
                              void* d_out, int out_size, void* d_ws, size_t ws_size,
                              hipStream_t stream) {
  const float* u     = (const float*)d_in[0];
  const float* Lre   = (const float*)d_in[1];
  const float* Lim   = (const float*)d_in[2];
  const float* Pre   = (const float*)d_in[3];
  const float* Pim   = (const float*)d_in[4];
  const float* Bre   = (const float*)d_in[5];
  const float* Bim   = (const float*)d_in[6];
  const float* Cri   = (const float*)d_in[7];
  const float* Dp    = (const float*)d_in[8];
  const float* lstep = (const float*)d_in[9];
  float* out = (float*)d_out;

  char* ws = (char*)d_ws;
  float2* a_ws   = (float2*)(ws);             //  32768 B : at_roots
  float*  K_ws   = (float*)(ws + 32768);      //  16384 B : K time domain
  float4* tp1_ws = (float4*)(ws + 49152);     //  32768 B : P1/P5 packs [8][256]
  float4* tp2_ws = (float4*)(ws + 81920);     //   2048 B : P2/P4 packs [8][16]
  float2* wp3_ws = (float2*)(ws + 83968);     //   2048 B : per-block W8192 base
  float2* H_ws   = (float2*)(ws + 86016);     //  32776 B : half-spectrum H[0..4096]
  float2* KdA_ws = (float2*)(ws + 118800);    //  32768 B : H[k] per (block,reg)
  float2* KdB_ws = (float2*)(ws + 151568);    //  32768 B : H[N-k] per (block,reg)

  hipLaunchKernelGGL(tables_kernel, dim3(10),   dim3(256), 0, stream,
                     tp1_ws, tp2_ws, wp3_ws);
  hipLaunchKernelGGL(cauchy_kernel, dim3(64),   dim3(64),  0, stream,
                     Lre, Lim, Pre, Pim, Bre, Bim, Cri, lstep, a_ws);
  hipLaunchKernelGGL(ktime_kernel,  dim3(1024), dim3(256), 0, stream, a_ws, K_ws);
  hipLaunchKernelGGL(hspec_kernel,  dim3(1025), dim3(256), 0, stream, K_ws, H_ws);
  hipLaunchKernelGGL(map_kernel,    dim3(16),   dim3(256), 0, stream,
                     H_ws, Dp, KdA_ws, KdB_ws);
  hipLaunchKernelGGL(conv_kernel,   dim3(NBH),  dim3(256), 0, stream,
                     u, tp1_ws, tp2_ws, wp3_ws, KdA_ws, KdB_ws, out);
}

// Round 11
// 119.106 us; speedup vs baseline: 1.6077x; 1.4448x over previous
//
#include <hip/hip_runtime.h>
#include <math.h>

#define LSEQ 4096
#define MFFT 8192
#define NM   64
#define NBH  4096
#define TMAIN 512

__device__ __forceinline__ float2 cmulf(float2 a, float2 b) {
  return make_float2(a.x*b.x - a.y*b.y, a.x*b.y + a.y*b.x);
}
// a * conj(b) -- conj is free (operand negation folds into the FMAs)
__device__ __forceinline__ float2 cmulc(float2 a, float2 b) {
  return make_float2(a.x*b.x + a.y*b.y, a.y*b.x - a.x*b.y);
}
__device__ __forceinline__ float2 caddf(float2 a, float2 b){ return make_float2(a.x+b.x, a.y+b.y); }
__device__ __forceinline__ float2 csubf(float2 a, float2 b){ return make_float2(a.x-b.x, a.y-b.y); }
__device__ __forceinline__ float2 conjf(float2 a){ return make_float2(a.x, -a.y); }

// ---- radix-4 butterflies (validated r1..r5 lineage) ----
__device__ __forceinline__ void r4_fwd(float2& x0, float2& x1, float2& x2, float2& x3,
                                       float2 w1, float2 w2, float2 w3) {
  float2 A = caddf(x0,x2), C = csubf(x0,x2);
  float2 B = caddf(x1,x3), D = csubf(x1,x3);
  float2 y1 = make_float2(C.x + D.y, C.y - D.x);   // C - iD
  float2 y3 = make_float2(C.x - D.y, C.y + D.x);   // C + iD
  x0 = caddf(A,B);
  x1 = cmulf(y1,w1);
  x2 = cmulf(csubf(A,B),w2);
  x3 = cmulf(y3,w3);
}
// inverse butterfly taking FORWARD twiddles (conjugate applied inside, free)
__device__ __forceinline__ void r4_invc(float2& y0, float2& y1, float2& y2, float2& y3,
                                        float2 w1, float2 w2, float2 w3) {
  float2 c1 = cmulc(y1,w1);
  float2 c2 = cmulc(y2,w2);
  float2 c3 = cmulc(y3,w3);
  float2 ap = caddf(y0,c2), bp = csubf(y0,c2);
  float2 cp = caddf(c1,c3);
  float2 dp = make_float2(c3.y - c1.y, c1.x - c3.x);
  y0 = caddf(ap,cp); y1 = caddf(bp,dp); y2 = csubf(ap,cp); y3 = csubf(bp,dp);
}

// compile-time constants for the wA=1 (P3) stage
#define DECL_CONSTS \
  const float C16R[4]={1.f,0.9238795325112867f,0.7071067811865476f,0.3826834323650898f}; \
  const float C16I[4]={0.f,-0.3826834323650898f,-0.7071067811865476f,-0.9238795325112867f}; \
  const float C8R[4] ={1.f,0.7071067811865476f,0.f,-0.7071067811865476f}; \
  const float C8I[4] ={0.f,-0.7071067811865476f,-1.f,-0.7071067811865476f}; \
  const float C163R[4]={1.f,0.3826834323650898f,-0.7071067811865476f,-0.9238795325112867f}; \
  const float C163I[4]={0.f,-0.9238795325112867f,-0.7071067811865476f,0.3826834323650898f};

// const-twiddle fused radix-16 (P3): compiler folds all constant products
__device__ __forceinline__ void r16_fwd1(float2 x[16]) {
  DECL_CONSTS
  #pragma unroll
  for (int k0 = 0; k0 < 4; k0++)
    r4_fwd(x[k0], x[k0+4], x[k0+8], x[k0+12],
           make_float2(C16R[k0],C16I[k0]), make_float2(C8R[k0],C8I[k0]),
           make_float2(C163R[k0],C163I[k0]));
  #pragma unroll
  for (int q = 0; q < 4; q++)
    r4_fwd(x[4*q], x[4*q+1], x[4*q+2], x[4*q+3],
           make_float2(1.f,0.f), make_float2(1.f,0.f), make_float2(1.f,0.f));
}
__device__ __forceinline__ void r16_inv1(float2 x[16]) {
  DECL_CONSTS
  #pragma unroll
  for (int q = 0; q < 4; q++)
    r4_invc(x[4*q], x[4*q+1], x[4*q+2], x[4*q+3],
            make_float2(1.f,0.f), make_float2(1.f,0.f), make_float2(1.f,0.f));
  #pragma unroll
  for (int k0 = 0; k0 < 4; k0++)
    r4_invc(x[k0], x[k0+4], x[k0+8], x[k0+12],
            make_float2(C16R[k0],C16I[k0]), make_float2(C8R[k0],C8I[k0]),
            make_float2(C163R[k0],C163I[k0]));
}

// table-twiddle fused radix-16: tp[q] packs tw[2q],tw[2q+1];
// tw layout: [0..3]=w1[k0], [4..7]=w2[k0], [8..11]=w3[k0], [12]=wB, [13]=wB2, [14]=wB3
__device__ __forceinline__ void r16_fwd_t(float2 x[16], const float4 tp[8]) {
  float2 tw[16];
  #pragma unroll
  for (int q = 0; q < 8; q++) {
    tw[2*q]   = make_float2(tp[q].x, tp[q].y);
    tw[2*q+1] = make_float2(tp[q].z, tp[q].w);
  }
  #pragma unroll
  for (int k0 = 0; k0 < 4; k0++)
    r4_fwd(x[k0], x[k0+4], x[k0+8], x[k0+12], tw[k0], tw[4+k0], tw[8+k0]);
  #pragma unroll
  for (int q = 0; q < 4; q++)
    r4_fwd(x[4*q], x[4*q+1], x[4*q+2], x[4*q+3], tw[12], tw[13], tw[14]);
}
__device__ __forceinline__ void r16_inv_t(float2 x[16], const float4 tp[8]) {
  float2 tw[16];
  #pragma unroll
  for (int q = 0; q < 8; q++) {
    tw[2*q]   = make_float2(tp[q].x, tp[q].y);
    tw[2*q+1] = make_float2(tp[q].z, tp[q].w);
  }
  #pragma unroll
  for (int q = 0; q < 4; q++)
    r4_invc(x[4*q], x[4*q+1], x[4*q+2], x[4*q+3], tw[12], tw[13], tw[14]);
  #pragma unroll
  for (int k0 = 0; k0 < 4; k0++)
    r4_invc(x[k0], x[k0+4], x[k0+8], x[k0+12], tw[k0], tw[4+k0], tw[8+k0]);
}

// ---------------- prep: twiddle-pack tables, ONE ENTRY PER THREAD (wide grid) -------------
// r5's version computed 16 Wexp per thread on a 3-block grid -> serial fp64-sincos hot spot
// (~10-15us steady, 114us cold). Same values, one float4 entry per thread, 18x256 grid.
// Slot exponents (1/8192 units), wA exponent a (a=t for tp1, a=16j for tp2):
//   s in 0..3 : a + 512 s     s in 4..7 : 2a + 1024(s-4)    s in 8..11: 3a + 1536(s-8)
//   s=12: 4a   s=13: 8a   s=14: 12a   s=15: identity (1,0)
__device__ __forceinline__ float2 W8192e(long long e) {
  double ang = -2.0*M_PI*(double)(e & (MFFT-1))/(double)MFFT;
  return make_float2((float)cos(ang), (float)sin(ang));
}
__device__ __forceinline__ long long slotE(int s, long long a) {
  if (s < 4)  return a + 512LL*s;
  if (s < 8)  return 2LL*a + 1024LL*(s-4);
  if (s < 12) return 3LL*a + 1536LL*(s-8);
  if (s == 12) return 4LL*a;
  if (s == 13) return 8LL*a;
  if (s == 14) return 12LL*a;
  return 0;
}
__global__ void tables_kernel(float4* __restrict__ tp1, float4* __restrict__ tp2,
                              float2* __restrict__ ct2) {
  int idx = blockIdx.x*blockDim.x + threadIdx.x;
  if (idx < 4096) {                       // tp1[q*512+t]
    int q = idx >> 9, t = idx & 511;
    float2 wa = W8192e(slotE(2*q, t));
    float2 wb = (2*q+1 == 15) ? make_float2(1.f,0.f) : W8192e(slotE(2*q+1, t));
    tp1[q*512 + t] = make_float4(wa.x, wa.y, wb.x, wb.y);
  } else if (idx < 4352) {                // tp2[q*32+j], a = 16j
    int r = idx - 4096; int q = r >> 5, j = r & 31;
    long long a = 16LL*j;
    float2 wa = W8192e(slotE(2*q, a));
    float2 wb = (2*q+1 == 15) ? make_float2(1.f,0.f) : W8192e(slotE(2*q+1, a));
    tp2[q*32 + j] = make_float4(wa.x, wa.y, wb.x, wb.y);
  } else if (idx < 4368) {                // ct2[c] = W^{256c}
    int c = idx - 4352;
    ct2[c] = W8192e(256LL*c);
  }
}

// ---------------- prep: at_roots[k] via 4 Cauchy dots (double precision) ----------------
__global__ void cauchy_kernel(const float* __restrict__ Lre, const float* __restrict__ Lim,
                              const float* __restrict__ Pre, const float* __restrict__ Pim,
                              const float* __restrict__ Bre, const float* __restrict__ Bim,
                              const float* __restrict__ Cri, const float* __restrict__ lstep,
                              float2* __restrict__ a_out) {
  int k = blockIdx.x*blockDim.x + threadIdx.x;
  if (k >= LSEQ) return;
  double step = exp((double)lstep[0]);
  double ang = -2.0*M_PI*(double)k/(double)LSEQ;
  double wr = cos(ang), wi = sin(ang);
  double nr = 1.0 - wr, ni = -wi;
  double dr = 1.0 + wr, di = wi;
  double dn = dr*dr + di*di;
  double gre = (2.0/step) * (nr*dr + ni*di)/dn;
  double gim = (2.0/step) * (ni*dr - nr*di)/dn;
  double cre = 2.0*dr/dn, cim = -2.0*di/dn;
  double k00r=0,k00i=0,k01r=0,k01i=0,k10r=0,k10i=0,k11r=0,k11i=0;
  for (int n = 0; n < NM; n++) {
    double lre = Lre[n], lim = Lim[n];
    double pre = Pre[n], pim = Pim[n];
    double bre = Bre[n], bim = Bim[n];
    double ccr = Cri[2*n], cci = Cri[2*n+1];
    double er = gre - lre, ei = gim - lim;
    double inv = 1.0/(er*er + ei*ei);
    double ir =  er*inv, ii = -ei*inv;
    double v00r = ccr*bre + cci*bim, v00i = ccr*bim - cci*bre;
    double v01r = ccr*pre + cci*pim, v01i = ccr*pim - cci*pre;
    double v10r = pre*bre + pim*bim, v10i = pre*bim - pim*bre;
    double v11r = pre*pre + pim*pim, v11i = 0.0;
    k00r += v00r*ir - v00i*ii;  k00i += v00r*ii + v00i*ir;
    k01r += v01r*ir - v01i*ii;  k01i += v01r*ii + v01i*ir;
    k10r += v10r*ir - v10i*ii;  k10i += v10r*ii + v10i*ir;
    k11r += v11r*ir - v11i*ii;  k11i += v11r*ii + v11i*ir;
  }
  double numr = k01r*k10r - k01i*k10i, numi = k01r*k10i + k01i*k10r;
  double der = 1.0 + k11r, dei = k11i;
  double dinv = 1.0/(der*der + dei*dei);
  double qr = (numr*der + numi*dei)*dinv;
  double qi = (numi*der - numr*dei)*dinv;
  double tr = k00r - qr, ti = k00i - qi;
  double ar = cre*tr - cim*ti, ai = cre*ti + cim*tr;
  a_out[k] = make_float2((float)ar, (float)ai);
}

// ---------------- prep: K[l] = Re(IDFT_L(a))[l], 64 lanes per output ----------------
__global__ void ktime_kernel(const float2* __restrict__ a, float* __restrict__ K) {
  int lane = threadIdx.x & 63;
  int l = blockIdx.x * (blockDim.x >> 6) + (threadIdx.x >> 6);
  if (l >= LSEQ) return;
  double ang0 = 2.0*M_PI*(double)((l*lane) & (LSEQ-1))/(double)LSEQ;
  double tr = cos(ang0), ti = sin(ang0);
  double ang1 = 2.0*M_PI*(double)(l & 63)/64.0;
  double wr = cos(ang1), wi = sin(ang1);
  double acc = 0.0;
  for (int k = 0; k < 64; k++) {
    float2 ak = a[lane + (k << 6)];
    acc += (double)ak.x*tr - (double)ak.y*ti;
    double ntr = tr*wr - ti*wi;
    ti = tr*wi + ti*wr;
    tr = ntr;
  }
  for (int off = 32; off > 0; off >>= 1) acc += __shfl_down(acc, off);
  if (lane == 0) K[l] = (float)(acc/(double)LSEQ);
}

// ---------------- prep: Kd = fwd chain(pad(K + D*delta)) / M ----------------
__global__ void kd_kernel(const float* __restrict__ K, const float* __restrict__ Dp,
                          const float4* __restrict__ tp1, const float4* __restrict__ tp2,
                          const float2* __restrict__ ct2, float2* __restrict__ Kd) {
  __shared__ float2 z[MFFT];
  const int tid = threadIdx.x;
  float2 x[16];
  float4 tpr[8];
  #pragma unroll
  for (int q = 0; q < 8; q++) tpr[q] = tp1[(q<<9) + tid];
  // P1 (t=512); fold D*u into the kernel: K'[0] = K[0] + D
  #pragma unroll
  for (int k = 0; k < 8; k++) {
    float v = K[tid + 512*k];
    if (tid == 0 && k == 0) v += Dp[0];
    x[k] = make_float2(v, 0.f);
  }
  #pragma unroll
  for (int k = 8; k < 16; k++) x[k] = make_float2(0.f, 0.f);
  r16_fwd_t(x, tpr);
  {
    int xc = (tid >> 5) & 15; int p0 = tid ^ xc;
    #pragma unroll
    for (int k = 0; k < 16; k++) z[p0 + 512*k] = x[k];
  }
  __syncthreads();
  // P2 (t=32) + r2(s=16) via shfl
  const int j5 = tid & 31;
  const int Gb = (tid >> 5) << 9;
  float4 tq[8];
  #pragma unroll
  for (int q = 0; q < 8; q++) tq[q] = tp2[(q<<5) + j5];
  #pragma unroll
  for (int k = 0; k < 16; k++) x[k] = z[Gb + 32*k + (j5 ^ k)];
  r16_fwd_t(x, tq);
  {
    bool hi = (tid >> 4) & 1;
    float2 w32 = ct2[tid & 15];
    float2 weff = hi ? w32 : make_float2(1.f, 0.f);
    float s = hi ? -1.f : 1.f;
    #pragma unroll
    for (int k = 0; k < 16; k++) {
      float rx = __shfl_xor(x[k].x, 16);
      float ry = __shfl_xor(x[k].y, 16);
      float2 pre = make_float2(fmaf(x[k].x, s, rx), fmaf(x[k].y, s, ry));
      x[k] = cmulf(pre, weff);
    }
  }
  #pragma unroll
  for (int k = 0; k < 16; k++) z[Gb + 32*k + (j5 ^ k)] = x[k];
  __syncthreads();
  // P3: consecutive, const-twiddle r16, scale, store
  {
    int xc = (tid >> 1) & 15; int b16 = tid << 4;
    #pragma unroll
    for (int c = 0; c < 16; c++) x[c] = z[b16 + (c ^ xc)];
    r16_fwd1(x);
    const float sc = 1.0f/(float)MFFT;
    #pragma unroll
    for (int c = 0; c < 16; c++)
      Kd[b16 + c] = make_float2(x[c].x*sc, x[c].y*sc);
  }
}

// ---------------- main: 2 rows per block, 5 passes, 2 full barriers ----------------
// (512,2): VGPR cap 128, r5-measured allocation 80 -> zero spill, 2 blocks x 8 waves/CU.
// P2->P3 and P3->P4 are class-local (class c = tid>>5 touches only z[512c..512c+512),
// threads [32c,32c+32) = same wave), so same-wave LDS ordering replaces __syncthreads.
__global__ __launch_bounds__(TMAIN, 2)
void conv_kernel(const float* __restrict__ u,
                 const float4* __restrict__ tp1, const float4* __restrict__ tp2,
                 const float2* __restrict__ ct2, const float2* __restrict__ Kd,
                 float* __restrict__ out) {
  __shared__ float2 z[MFFT];
  const int tid = threadIdx.x;
  const int r0 = blockIdx.x, r1 = blockIdx.x + (NBH/2);
  const float* u0 = u + (size_t)r0*LSEQ;
  const float* u1 = u + (size_t)r1*LSEQ;
  float2 x[16];
  // ---- P1: global->regs, r16 fwd (t=512), regs->LDS ----
  {
    float4 tpr[8];
    #pragma unroll
    for (int q = 0; q < 8; q++) tpr[q] = tp1[(q<<9) + tid];
    #pragma unroll
    for (int k = 0; k < 8; k++)
      x[k] = make_float2(u0[tid + 512*k], u1[tid + 512*k]);
    #pragma unroll
    for (int k = 8; k < 16; k++) x[k] = make_float2(0.f, 0.f);
    r16_fwd_t(x, tpr);
    int xc = (tid >> 5) & 15; int p0 = tid ^ xc;
    #pragma unroll
    for (int k = 0; k < 16; k++) z[p0 + 512*k] = x[k];
  }
  __syncthreads();
  // ---- P2: r16 fwd (t=32) + r2(s=16) tail via shfl_xor(16) ----
  const int j5 = tid & 31;
  const int Gb = (tid >> 5) << 9;
  const bool hi = (tid >> 4) & 1;
  const float2 w32 = ct2[tid & 15];
  const float sgn = hi ? -1.f : 1.f;
  {
    float4 tq[8];
    #pragma unroll
    for (int q = 0; q < 8; q++) tq[q] = tp2[(q<<5) + j5];
    #pragma unroll
    for (int k = 0; k < 16; k++) x[k] = z[Gb + 32*k + (j5 ^ k)];
    r16_fwd_t(x, tq);
    float2 weff = hi ? w32 : make_float2(1.f, 0.f);
    #pragma unroll
    for (int k = 0; k < 16; k++) {
      float rx = __shfl_xor(x[k].x, 16);
      float ry = __shfl_xor(x[k].y, 16);
      float2 pre = make_float2(fmaf(x[k].x, sgn, rx), fmaf(x[k].y, sgn, ry));
      x[k] = cmulf(pre, weff);
    }
    #pragma unroll
    for (int k = 0; k < 16; k++) z[Gb + 32*k + (j5 ^ k)] = x[k];
  }
  __builtin_amdgcn_wave_barrier();   // class-local: same-wave LDS ordering suffices
  // ---- P3: consecutive; const r16 fwd; x Kd; const r16 inv ----
  {
    int xc = (tid >> 1) & 15; int b16 = tid << 4;
    #pragma unroll
    for (int c = 0; c < 16; c++) x[c] = z[b16 + (c ^ xc)];
    float4 kd[8];
    const float4* Kd4 = (const float4*)(Kd + b16);
    #pragma unroll
    for (int q = 0; q < 8; q++) kd[q] = Kd4[q];
    r16_fwd1(x);
    #pragma unroll
    for (int c = 0; c < 8; c++) {
      x[2*c]   = cmulf(x[2*c],   make_float2(kd[c].x, kd[c].y));
      x[2*c+1] = cmulf(x[2*c+1], make_float2(kd[c].z, kd[c].w));
    }
    r16_inv1(x);
    #pragma unroll
    for (int c = 0; c < 16; c++) z[b16 + (c ^ xc)] = x[c];
  }
  __builtin_amdgcn_wave_barrier();   // class-local again
  // ---- P4: inv r2(s=16) head via shfl + r16 inv (t=32) ----
  {
    #pragma unroll
    for (int k = 0; k < 16; k++) x[k] = z[Gb + 32*k + (j5 ^ k)];
    float2 weffc = hi ? conjf(w32) : make_float2(1.f, 0.f);
    #pragma unroll
    for (int k = 0; k < 16; k++) {
      float2 v = cmulf(x[k], weffc);
      float rx = __shfl_xor(v.x, 16);
      float ry = __shfl_xor(v.y, 16);
      x[k] = make_float2(fmaf(v.x, sgn, rx), fmaf(v.y, sgn, ry));
    }
    float4 tq[8];
    #pragma unroll
    for (int q = 0; q < 8; q++) tq[q] = tp2[(q<<5) + j5];
    r16_inv_t(x, tq);
    #pragma unroll
    for (int k = 0; k < 16; k++) z[Gb + 32*k + (j5 ^ k)] = x[k];
  }
  __syncthreads();
  // ---- P5: r16 inv (t=512), regs->global (D already folded into Kd) ----
  {
    float4 tpr[8];
    #pragma unroll
    for (int q = 0; q < 8; q++) tpr[q] = tp1[(q<<9) + tid];
    int xc = (tid >> 5) & 15; int p0 = tid ^ xc;
    #pragma unroll
    for (int k = 0; k < 16; k++) x[k] = z[p0 + 512*k];
    r16_inv_t(x, tpr);
    float* o0 = out + (size_t)r0*LSEQ;
    float* o1 = out + (size_t)r1*LSEQ;
    #pragma unroll
    for (int k = 0; k < 8; k++) {
      int idx = tid + 512*k;
      o0[idx] = x[k].x;
      o1[idx] = x[k].y;
    }
  }
}

extern "C" void kernel_launch(void* const* d_in, const int* in_sizes, int n_in,
                              void* d_out, int out_size, void* d_ws, size_t ws_size,
                              hipStream_t stream) {
  const float* u     = (const float*)d_in[0];
  const float* Lre   = (const float*)d_in[1];
  const float* Lim   = (const float*)d_in[2];
  const float* Pre   = (const float*)d_in[3];
  const float* Pim   = (const float*)d_in[4];
  const float* Bre   = (const float*)d_in[5];
  const float* Bim   = (const float*)d_in[6];
  const float* Cri   = (const float*)d_in[7];
  const float* Dp    = (const float*)d_in[8];
  const float* lstep = (const float*)d_in[9];
  float* out = (float*)d_out;

  char* ws = (char*)d_ws;
  float2* a_ws  = (float2*)(ws);            //  32768 B : at_roots
  float*  K_ws  = (float*)(ws + 32768);     //  16384 B : K time domain
  float2* Kd_ws = (float2*)(ws + 49152);    //  65536 B : Kd (logical order, /M, +D folded)
  float4* tp1_ws= (float4*)(ws + 114688);   //  65536 B : P1/P5 twiddle packs [8][512]
  float4* tp2_ws= (float4*)(ws + 180224);   //   4096 B : P2/P4 twiddle packs [8][32]
  float2* ct2_ws= (float2*)(ws + 184320);   //    128 B : r2-stage twiddles

  hipLaunchKernelGGL(tables_kernel, dim3(18),   dim3(256), 0, stream,
                     tp1_ws, tp2_ws, ct2_ws);
  hipLaunchKernelGGL(cauchy_kernel, dim3(64),   dim3(64),  0, stream,
                     Lre, Lim, Pre, Pim, Bre, Bim, Cri, lstep, a_ws);
  hipLaunchKernelGGL(ktime_kernel,  dim3(1024), dim3(256), 0, stream, a_ws, K_ws);
  hipLaunchKernelGGL(kd_kernel,     dim3(1),    dim3(TMAIN), 0, stream,
                     K_ws, Dp, tp1_ws, tp2_ws, ct2_ws, Kd_ws);
  hipLaunchKernelGGL(conv_kernel,   dim3(NBH/2), dim3(TMAIN), 0, stream,
                     u, tp1_ws, tp2_ws, ct2_ws, Kd_ws, out);
}